// Round 3
// baseline (180.403 us; speedup 1.0000x reference)
//
#include <hip/hip_runtime.h>
#include <hip/hip_bf16.h>
#include <math.h>

// TinyMoE: out = sum_e softmax(x@Wr)[e] * (gelu(x@w1[e]+b1[e]) @ w2[e] + b2[e])
// Two dense GEMMs: [32768x512]@[512x256] -> gelu/scale -> @[256x512(+b2 rows)]
// bf16 MFMA (16x16x32), fp32 router/softmax/gelu.
// R3: no X staging -- GEMM1 A-frags straight from global with inline cvt
// (x tile stays hot in L2; loads overlap MFMA). Barriers 4 -> 2. LDS = H tile
// only (~20 KB). 32 tokens/WG, grid 1024 (fully co-resident).

typedef short v8s __attribute__((ext_vector_type(8)));
typedef float v4f __attribute__((ext_vector_type(4)));

#define HS 296   // H LDS row stride: 288 (=256 + 4 b2-weight rows + 28 zero pad) + 8 pad
#define TT 32    // tokens per WG

__device__ __forceinline__ unsigned short f2bf(float f) {
    unsigned int u = __builtin_bit_cast(unsigned int, f);
    u += 0x7fffu + ((u >> 16) & 1u);
    return (unsigned short)(u >> 16);
}

__device__ __forceinline__ v8s cvt8(float4 a, float4 b) {
    v8s r;
    r[0] = (short)f2bf(a.x); r[1] = (short)f2bf(a.y);
    r[2] = (short)f2bf(a.z); r[3] = (short)f2bf(a.w);
    r[4] = (short)f2bf(b.x); r[5] = (short)f2bf(b.y);
    r[6] = (short)f2bf(b.z); r[7] = (short)f2bf(b.w);
    return r;
}

// ---- prep: pack weights into bf16 MFMA B-fragment layout in workspace ----
// Block = 16(N) x 32(K) bf16, stored as [n_local*32 + k_local], 512 elems = 1KB.
// Lane l reads 16B at ((l&15)*32 + (l>>4)*8)*2 -> B[k][n], n=l&15, k=(l>>4)*8+j.
__global__ void moe_prep(const float* __restrict__ w1,   // (4,512,64)
                         const float* __restrict__ w2,   // (4,64,512)
                         const float* __restrict__ b2,   // (4,512)
                         const float* __restrict__ rw,   // (512,4)
                         unsigned short* __restrict__ w1p,
                         unsigned short* __restrict__ w2p,
                         unsigned short* __restrict__ rp) {
    int idx = blockIdx.x * 256 + threadIdx.x;
    if (idx < 131072) {
        // W1' [K=512][N=256], block = kb*16 + cb
        int block = idx >> 9, within = idx & 511;
        int kb = block >> 4, cb = block & 15;
        int n = within >> 5, kl = within & 31;
        int k = kb * 32 + kl;
        int col = cb * 16 + n;
        int e = col >> 6, h = col & 63;
        w1p[idx] = f2bf(w1[(e * 512 + k) * 64 + h]);
    } else if (idx < 131072 + 147456) {
        // W2' [Kpad=288][N=512], block = kb*32 + cb. k in [256,260) = b2 rows, >=260 zero.
        int op = idx - 131072;
        int block = op >> 9, within = op & 511;
        int kb = block >> 5, cb = block & 31;
        int n = within >> 5, kl = within & 31;
        int k = kb * 32 + kl;
        int d = cb * 16 + n;
        float v = 0.f;
        if (k < 256) {
            int e = k >> 6, h = k & 63;
            v = w2[(e * 64 + h) * 512 + d];
        } else if (k < 260) {
            v = b2[(k - 256) * 512 + d];
        }
        w2p[op] = f2bf(v);
    } else if (idx < 131072 + 147456 + 8192) {
        // router W [K=512][N=16] (cols >=4 zero), block = kb
        int op = idx - (131072 + 147456);
        int kb = op >> 9, within = op & 511;
        int n = within >> 5, kl = within & 31;
        int k = kb * 32 + kl;
        float v = (n < 4) ? rw[k * 4 + n] : 0.f;
        rp[op] = f2bf(v);
    }
}

// ---- main fused kernel ----
__global__ __launch_bounds__(256, 5)
void moe_main(const float* __restrict__ x,
              const float* __restrict__ rb,
              const float* __restrict__ b1,
              const unsigned short* __restrict__ w1p,
              const unsigned short* __restrict__ w2p,
              const unsigned short* __restrict__ rp,
              float* __restrict__ out) {
    // H tile [TT][HS] bf16 = 18944 B. No X tile -- A-frags come from global.
    __shared__ __align__(16) unsigned short lh[TT * HS];
    __shared__ float llog[TT * 4];
    __shared__ float lw[TT * 4];

    const int tid  = threadIdx.x;
    const int lane = tid & 63, wv = tid >> 6;
    const int lr = lane & 15, lq = lane >> 4;   // A: m=lr, k=lq*8+j ; B: n=lr ; C: col=lr, row=lq*4+r
    const long t0 = (long)blockIdx.x * TT;

    // ---- phase 1: router (waves 0,1 only; within-wave) ----
    if (wv < 2) {
        const float* xr = x + (t0 + 16 * wv + lr) * 512 + lq * 8;
        v4f accR; accR[0] = accR[1] = accR[2] = accR[3] = 0.f;
        #pragma unroll 4
        for (int kb = 0; kb < 16; ++kb) {
            float4 f0 = *(const float4*)(xr + kb * 32);
            float4 f1 = *(const float4*)(xr + kb * 32 + 4);
            v8s a = cvt8(f0, f1);
            v8s b = *(const v8s*)(const void*)&rp[kb * 512 + lr * 32 + lq * 8];
            accR = __builtin_amdgcn_mfma_f32_16x16x32_bf16(a, b, accR, 0, 0, 0);
        }
        if (lr < 4) {
            #pragma unroll
            for (int r = 0; r < 4; ++r)
                llog[(16 * wv + lq * 4 + r) * 4 + lr] = accR[r];
        }
        asm volatile("s_waitcnt lgkmcnt(0)" ::: "memory");
        if (lane < 16) {
            int t = 16 * wv + lane;
            float l[4];
            #pragma unroll
            for (int e = 0; e < 4; ++e) l[e] = llog[t * 4 + e] + rb[e];
            float mx = fmaxf(fmaxf(l[0], l[1]), fmaxf(l[2], l[3]));
            float ex[4], s = 0.f;
            #pragma unroll
            for (int e = 0; e < 4; ++e) { ex[e] = expf(l[e] - mx); s += ex[e]; }
            float inv = 1.f / s;
            #pragma unroll
            for (int e = 0; e < 4; ++e) lw[t * 4 + e] = ex[e] * inv;
        }
    }

    // ---- phase 2: GEMM1  C1[32][256] = X @ W1'; wave w owns cols [64w,64w+64) = expert w
    //      A-frags straight from global x (tile hot in L2 after first touch) ----
    v4f acc1[2][4];
    #pragma unroll
    for (int mt = 0; mt < 2; ++mt)
        #pragma unroll
        for (int nt = 0; nt < 4; ++nt)
            acc1[mt][nt][0] = acc1[mt][nt][1] = acc1[mt][nt][2] = acc1[mt][nt][3] = 0.f;

    {
        const float* xr0 = x + (t0 + lr) * 512 + lq * 8;        // mt=0 row
        const float* xr1 = xr0 + 16 * 512;                      // mt=1 row
        #pragma unroll 2
        for (int kb = 0; kb < 16; ++kb) {
            float4 f00 = *(const float4*)(xr0 + kb * 32);
            float4 f01 = *(const float4*)(xr0 + kb * 32 + 4);
            float4 f10 = *(const float4*)(xr1 + kb * 32);
            float4 f11 = *(const float4*)(xr1 + kb * 32 + 4);
            v8s a0 = cvt8(f00, f01);
            v8s a1 = cvt8(f10, f11);
            v8s b[4];
            #pragma unroll
            for (int nt = 0; nt < 4; ++nt)
                b[nt] = *(const v8s*)(const void*)&w1p[(size_t)(kb * 16 + wv * 4 + nt) * 512 + lr * 32 + lq * 8];
            #pragma unroll
            for (int nt = 0; nt < 4; ++nt) {
                acc1[0][nt] = __builtin_amdgcn_mfma_f32_16x16x32_bf16(a0, b[nt], acc1[0][nt], 0, 0, 0);
                acc1[1][nt] = __builtin_amdgcn_mfma_f32_16x16x32_bf16(a1, b[nt], acc1[1][nt], 0, 0, 0);
            }
        }
    }
    __syncthreads();   // publishes lw (router) ; nothing has touched lh yet

    // epilogue: gelu(v+b1)*router_weight -> bf16 H[32][288] (cols 256..259 = router wts for b2 rows)
    {
        float b1v[4];
        #pragma unroll
        for (int nt = 0; nt < 4; ++nt) b1v[nt] = b1[wv * 64 + nt * 16 + lr];
        #pragma unroll
        for (int mt = 0; mt < 2; ++mt) {
            #pragma unroll
            for (int r = 0; r < 4; ++r) {
                int row = 16 * mt + lq * 4 + r;
                float wt = lw[row * 4 + wv];
                #pragma unroll
                for (int nt = 0; nt < 4; ++nt) {
                    float v = acc1[mt][nt][r] + b1v[nt];
                    float g = 0.5f * v * (1.f + erff(v * 0.70710678118f)) * wt;
                    lh[row * HS + wv * 64 + nt * 16 + lr] = f2bf(g);
                }
            }
        }
        // append router-weight cols (k=256..259) and zero pad (260..287)
        if (tid < 128) {
            int r = tid >> 2, e = tid & 3;
            lh[r * HS + 256 + e] = f2bf(lw[tid]);
            #pragma unroll
            for (int i = 0; i < 7; ++i)
                lh[r * HS + 260 + e + 4 * i] = 0;
        }
    }
    __syncthreads();

    // ---- phase 3: GEMM2  OUT[32][512] = H[32][288] @ W2'; wave w owns cols [128w,128w+128)
    //      2 N-passes of 64 cols to cap register pressure ----
    float* ot = out + t0 * 512;
    for (int np = 0; np < 2; ++np) {
        v4f acc2[2][4];
        #pragma unroll
        for (int mt = 0; mt < 2; ++mt)
            #pragma unroll
            for (int nt = 0; nt < 4; ++nt)
                acc2[mt][nt][0] = acc2[mt][nt][1] = acc2[mt][nt][2] = acc2[mt][nt][3] = 0.f;

        for (int kb = 0; kb < 9; ++kb) {
            v8s a[2], b[4];
            #pragma unroll
            for (int mt = 0; mt < 2; ++mt)
                a[mt] = *(const v8s*)(const void*)&lh[(16 * mt + lr) * HS + kb * 32 + lq * 8];
            #pragma unroll
            for (int nt = 0; nt < 4; ++nt)
                b[nt] = *(const v8s*)(const void*)&w2p[(size_t)(kb * 32 + wv * 8 + np * 4 + nt) * 512 + lr * 32 + lq * 8];
            #pragma unroll
            for (int mt = 0; mt < 2; ++mt)
                #pragma unroll
                for (int nt = 0; nt < 4; ++nt)
                    acc2[mt][nt] = __builtin_amdgcn_mfma_f32_16x16x32_bf16(a[mt], b[nt], acc2[mt][nt], 0, 0, 0);
        }

        #pragma unroll
        for (int mt = 0; mt < 2; ++mt)
            #pragma unroll
            for (int nt = 0; nt < 4; ++nt)
                #pragma unroll
                for (int r = 0; r < 4; ++r) {
                    int row = 16 * mt + lq * 4 + r;
                    int col = 128 * wv + 64 * np + 16 * nt + lr;
                    ot[row * 512 + col] = acc2[mt][nt][r];
                }
    }
}

extern "C" void kernel_launch(void* const* d_in, const int* in_sizes, int n_in,
                              void* d_out, int out_size, void* d_ws, size_t ws_size,
                              hipStream_t stream) {
    const float* x  = (const float*)d_in[0];
    const float* rw = (const float*)d_in[1];
    const float* rb = (const float*)d_in[2];
    const float* w1 = (const float*)d_in[3];
    const float* b1 = (const float*)d_in[4];
    const float* w2 = (const float*)d_in[5];
    const float* b2 = (const float*)d_in[6];

    unsigned short* w1p = (unsigned short*)d_ws;      // 131072 elems
    unsigned short* w2p = w1p + 131072;               // 147456 elems
    unsigned short* rp  = w2p + 147456;               // 8192 elems  (total ~573 KB)

    moe_prep<<<1120, 256, 0, stream>>>(w1, w2, b2, rw, w1p, w2p, rp);
    moe_main<<<1024, 256, 0, stream>>>(x, rb, b1, w1p, w2p, rp, (float*)d_out);
}